// Round 1
// baseline (257.126 us; speedup 1.0000x reference)
//
#include <hip/hip_runtime.h>
#include <hip/hip_bf16.h>
#include <cstdint>

typedef __attribute__((ext_vector_type(8))) __bf16 bf16x8;
typedef __attribute__((ext_vector_type(4))) float f32x4;
typedef unsigned short u16;
typedef unsigned int u32;

struct alignas(8) U16x4 { u16 x, y, z, w; };

__device__ __forceinline__ u16 f2b(float x) {
    u32 u = __builtin_bit_cast(u32, x);
    u += 0x7fffu + ((u >> 16) & 1u);   // round-to-nearest-even
    return (u16)(u >> 16);
}

// ---------------- kernel 1: f32 -> bf16 convert (hidden + concat weights) ----
__global__ __launch_bounds__(256) void cvt_kernel(
    const float* __restrict__ hs,
    const float* __restrict__ wq, const float* __restrict__ wk, const float* __restrict__ wv,
    u16* __restrict__ hsb, u16* __restrict__ wb)
{
    int i = blockIdx.x * 256 + threadIdx.x;       // float4 chunk index, exact grid
    const float4* src; u16* dst; int off;
    if (i < 1048576) { src = (const float4*)hs; dst = hsb; off = i; }
    else {
        int j = i - 1048576;                      // 3 * 262144 chunks
        int w = j >> 18;
        int o = j & 262143;
        src = (const float4*)(w == 0 ? wq : (w == 1 ? wk : wv));
        dst = wb + w * 1048576;
        off = o;
    }
    float4 v = src[off];
    U16x4 r; r.x = f2b(v.x); r.y = f2b(v.y); r.z = f2b(v.z); r.w = f2b(v.w);
    *(U16x4*)(dst + off * 4) = r;
}

// ---------------- kernel 2: QKV GEMM  C[4096,3072] = A[4096,1024] * W[3072,1024]^T
// writes Q,K as [B,H,S,64] bf16 and V transposed [B,H,64,S] bf16
#define LDSP 72   // padded LDS row stride (ushorts) for BK=64

__global__ __launch_bounds__(256) void qkv_gemm(
    const u16* __restrict__ A, const u16* __restrict__ W,
    const float* __restrict__ bq, const float* __restrict__ bk, const float* __restrict__ bv,
    u16* __restrict__ Qo, u16* __restrict__ Ko, u16* __restrict__ Vt)
{
    __shared__ u16 As[128 * LDSP];
    __shared__ u16 Bs[128 * LDSP];
    const int tid = threadIdx.x;
    const int lane = tid & 63, wid = tid >> 6;
    const int wr = (wid >> 1) * 64, wc = (wid & 1) * 64;  // wave sub-tile origin
    const int g = lane >> 4, c = lane & 15;
    const int bm = blockIdx.y, bn = blockIdx.x;

    f32x4 acc[4][4] = {};

    for (int k0 = 0; k0 < 1024; k0 += 64) {
        uint4 av[4], bv4[4];
        #pragma unroll
        for (int i = 0; i < 4; ++i) {
            int cidx = tid + i * 256;
            int row = cidx >> 3, col = (cidx & 7) * 8;
            av[i]  = *(const uint4*)(A + (bm * 128 + row) * 1024 + k0 + col);
            bv4[i] = *(const uint4*)(W + (bn * 128 + row) * 1024 + k0 + col);
        }
        __syncthreads();   // previous iter's fragment reads done before overwrite
        #pragma unroll
        for (int i = 0; i < 4; ++i) {
            int cidx = tid + i * 256;
            int row = cidx >> 3, col = (cidx & 7) * 8;
            *(uint4*)(As + row * LDSP + col) = av[i];
            *(uint4*)(Bs + row * LDSP + col) = bv4[i];
        }
        __syncthreads();
        #pragma unroll
        for (int kk = 0; kk < 2; ++kk) {
            bf16x8 af[4], bf[4];
            #pragma unroll
            for (int i = 0; i < 4; ++i)
                af[i] = *(const bf16x8*)(As + (wr + i * 16 + c) * LDSP + kk * 32 + g * 8);
            #pragma unroll
            for (int j = 0; j < 4; ++j)
                bf[j] = *(const bf16x8*)(Bs + (wc + j * 16 + c) * LDSP + kk * 32 + g * 8);
            #pragma unroll
            for (int i = 0; i < 4; ++i)
                #pragma unroll
                for (int j = 0; j < 4; ++j)
                    acc[i][j] = __builtin_amdgcn_mfma_f32_16x16x32_bf16(af[i], bf[j], acc[i][j], 0, 0, 0);
        }
    }

    const int region = (bn * 128) >> 10;             // 0=Q 1=K 2=V
    const float* bias = region == 0 ? bq : (region == 1 ? bk : bv);
    #pragma unroll
    for (int i = 0; i < 4; ++i) {
        int m0 = bm * 128 + wr + i * 16 + g * 4;     // output row base (4 rows)
        int b = m0 >> 10, s0 = m0 & 1023;
        #pragma unroll
        for (int j = 0; j < 4; ++j) {
            int n = bn * 128 + wc + j * 16 + c;
            int ncol = n & 1023;
            float bb = bias[ncol];
            int h = ncol >> 6, d = ncol & 63;
            int bh = b * 16 + h;
            if (region == 2) {
                U16x4 pk;
                pk.x = f2b(acc[i][j][0] + bb);
                pk.y = f2b(acc[i][j][1] + bb);
                pk.z = f2b(acc[i][j][2] + bb);
                pk.w = f2b(acc[i][j][3] + bb);
                *(U16x4*)(Vt + (bh * 64 + d) * 1024 + s0) = pk;   // s0 % 4 == 0
            } else {
                u16* dst = (region == 0) ? Qo : Ko;
                #pragma unroll
                for (int r = 0; r < 4; ++r)
                    dst[(bh * 1024 + s0 + r) * 64 + d] = f2b(acc[i][j][r] + bb);
            }
        }
    }
}

// ---------------- kernel 3: fused flash attention with post-softmax link mask
// grid: x = q-tile (16), y = b*16+h (64). 256 threads = 4 waves, 16 q-rows/wave.
__global__ __launch_bounds__(256) void attn_kernel(
    const u16* __restrict__ Q, const u16* __restrict__ K, const u16* __restrict__ Vt,
    const float* __restrict__ amask, const float* __restrict__ link,
    float* __restrict__ out)
{
    __shared__ u16 P[4][2][16 * 40];   // per-wave, double-buffered, padded (40)
    const int tid = threadIdx.x;
    const int lane = tid & 63, wid = tid >> 6;
    const int g = lane >> 4, c = lane & 15;
    const int qt = blockIdx.x;
    const int bh = blockIdx.y;
    const int b = bh >> 4, h = bh & 15;
    const int qbase = qt * 64 + wid * 16;

    const u16* Qh = Q + bh * 65536;
    const u16* Kh = K + bh * 65536;
    const u16* Vh = Vt + bh * 65536;
    const float* mk = amask + b * 1024;
    const float* lk = link + (size_t)b * 1048576;

    bf16x8 qf[2];
    #pragma unroll
    for (int x = 0; x < 2; ++x)
        qf[x] = *(const bf16x8*)(Qh + (qbase + c) * 64 + x * 32 + g * 8);

    float mrow[4] = {-INFINITY, -INFINITY, -INFINITY, -INFINITY};
    float lrow[4] = {0.f, 0.f, 0.f, 0.f};
    f32x4 ctx[4] = {};

    int par = 0;
    for (int kv = 0; kv < 1024; kv += 32, par ^= 1) {
        // scores: D[q(16), key(16)] x2 key-tiles, contraction over d=64 (2 MFMAs each)
        f32x4 sc[2] = {};
        #pragma unroll
        for (int t = 0; t < 2; ++t)
            #pragma unroll
            for (int x = 0; x < 2; ++x) {
                bf16x8 kf = *(const bf16x8*)(Kh + (kv + t * 16 + c) * 64 + x * 32 + g * 8);
                sc[t] = __builtin_amdgcn_mfma_f32_16x16x32_bf16(qf[x], kf, sc[t], 0, 0, 0);
            }
        float mk0 = mk[kv + c], mk1 = mk[kv + 16 + c];

        float p0[4], p1[4];
        #pragma unroll
        for (int r = 0; r < 4; ++r) {
            float s0 = sc[0][r] * 0.125f + mk0;
            float s1 = sc[1][r] * 0.125f + mk1;
            float vm = fmaxf(s0, s1);
            #pragma unroll
            for (int o = 1; o < 16; o <<= 1) vm = fmaxf(vm, __shfl_xor(vm, o, 64));
            float mn = fmaxf(mrow[r], vm);
            float sf = __expf(mrow[r] - mn);      // first iter: exp(-inf)=0
            float e0 = __expf(s0 - mn), e1 = __expf(s1 - mn);
            float rs = e0 + e1;
            #pragma unroll
            for (int o = 1; o < 16; o <<= 1) rs += __shfl_xor(rs, o, 64);
            lrow[r] = lrow[r] * sf + rs;          // denom WITHOUT link
            mrow[r] = mn;
            #pragma unroll
            for (int n = 0; n < 4; ++n) ctx[n][r] *= sf;
            p0[r] = e0; p1[r] = e1;
        }
        // multiplicative link mask folded into P (post-softmax semantics)
        u16* Pb = P[wid][par];
        int qg = qbase + g * 4;
        #pragma unroll
        for (int r = 0; r < 4; ++r) {
            float l0 = lk[(qg + r) * 1024 + kv + c];
            float l1 = lk[(qg + r) * 1024 + kv + 16 + c];
            Pb[(g * 4 + r) * 40 + c]      = f2b(p0[r] * l0);
            Pb[(g * 4 + r) * 40 + 16 + c] = f2b(p1[r] * l1);
        }
        __syncthreads();
        bf16x8 pf = *(const bf16x8*)(Pb + c * 40 + g * 8);   // A-frag: row=c, k=g*8
        #pragma unroll
        for (int n = 0; n < 4; ++n) {
            bf16x8 vf = *(const bf16x8*)(Vh + (n * 16 + c) * 1024 + kv + g * 8);
            ctx[n] = __builtin_amdgcn_mfma_f32_16x16x32_bf16(pf, vf, ctx[n], 0, 0, 0);
        }
    }

    #pragma unroll
    for (int r = 0; r < 4; ++r) {
        float inv = 1.0f / lrow[r];
        int q = qbase + g * 4 + r;
        #pragma unroll
        for (int n = 0; n < 4; ++n)
            out[(size_t)b * 1048576 + (size_t)q * 1024 + h * 64 + n * 16 + c] = ctx[n][r] * inv;
    }
}

extern "C" void kernel_launch(void* const* d_in, const int* in_sizes, int n_in,
                              void* d_out, int out_size, void* d_ws, size_t ws_size,
                              hipStream_t stream)
{
    (void)in_sizes; (void)n_in; (void)out_size; (void)ws_size;
    const float* hs    = (const float*)d_in[0];
    const float* amask = (const float*)d_in[1];
    const float* link  = (const float*)d_in[2];
    const float* Wq    = (const float*)d_in[3];
    const float* bq    = (const float*)d_in[4];
    const float* Wk    = (const float*)d_in[5];
    const float* bk    = (const float*)d_in[6];
    const float* Wv    = (const float*)d_in[7];
    const float* bv    = (const float*)d_in[8];
    float* out = (float*)d_out;

    char* ws = (char*)d_ws;
    u16* hsb = (u16*)ws;                   // 8 MiB  [4096][1024] bf16
    u16* wb  = (u16*)(ws + (8u  << 20));   // 6 MiB  [3072][1024] bf16 (Wq|Wk|Wv)
    u16* Qb  = (u16*)(ws + (14u << 20));   // 8 MiB  [B,H,S,64]
    u16* Kb  = (u16*)(ws + (22u << 20));   // 8 MiB  [B,H,S,64]
    u16* Vtb = (u16*)(ws + (30u << 20));   // 8 MiB  [B,H,64,S]

    cvt_kernel<<<7168, 256, 0, stream>>>(hs, Wq, Wk, Wv, hsb, wb);
    qkv_gemm<<<dim3(24, 32), 256, 0, stream>>>(hsb, wb, bq, bk, bv, Qb, Kb, Vtb);
    attn_kernel<<<dim3(16, 64), 256, 0, stream>>>(Qb, Kb, Vtb, amask, link, out);
}

// Round 2
// 215.874 us; speedup vs baseline: 1.1911x; 1.1911x over previous
//
#include <hip/hip_runtime.h>
#include <hip/hip_bf16.h>
#include <cstdint>

typedef __attribute__((ext_vector_type(8))) __bf16 bf16x8;
typedef __attribute__((ext_vector_type(4))) float f32x4;
typedef unsigned short u16;
typedef unsigned int u32;

struct alignas(8) U16x4 { u16 x, y, z, w; };

__device__ __forceinline__ u16 f2b(float x) {
    u32 u = __builtin_bit_cast(u32, x);
    u += 0x7fffu + ((u >> 16) & 1u);   // round-to-nearest-even
    return (u16)(u >> 16);
}
__device__ __forceinline__ u32 pack2(float a, float b) {
    return (u32)f2b(a) | ((u32)f2b(b) << 16);
}

// ---------------- kernel 1: f32 -> bf16 convert (hidden + concat weights) ----
__global__ __launch_bounds__(256) void cvt_kernel(
    const float* __restrict__ hs,
    const float* __restrict__ wq, const float* __restrict__ wk, const float* __restrict__ wv,
    u16* __restrict__ hsb, u16* __restrict__ wb)
{
    int i = blockIdx.x * 256 + threadIdx.x;       // float4 chunk index, exact grid
    const float4* src; u16* dst; int off;
    if (i < 1048576) { src = (const float4*)hs; dst = hsb; off = i; }
    else {
        int j = i - 1048576;                      // 3 * 262144 chunks
        int w = j >> 18;
        int o = j & 262143;
        src = (const float4*)(w == 0 ? wq : (w == 1 ? wk : wv));
        dst = wb + w * 1048576;
        off = o;
    }
    float4 v = src[off];
    U16x4 r; r.x = f2b(v.x); r.y = f2b(v.y); r.z = f2b(v.z); r.w = f2b(v.w);
    *(U16x4*)(dst + off * 4) = r;
}

// ---------------- kernel 2: QKV GEMM  C[4096,3072] = A[4096,1024] * W[3072,1024]^T
// m97 structure: global_load_lds width-16 staging into LINEAR LDS, 2-barrier K-loop.
// writes Q (pre-scaled by 0.125) and K as [B,H,S,64] bf16, V transposed [B,H,64,S] bf16
__global__ __launch_bounds__(256) void qkv_gemm(
    const u16* __restrict__ A, const u16* __restrict__ W,
    const float* __restrict__ bq, const float* __restrict__ bk, const float* __restrict__ bv,
    u16* __restrict__ Qo, u16* __restrict__ Ko, u16* __restrict__ Vt)
{
    __shared__ u16 As[128 * 64];
    __shared__ u16 Bs[128 * 64];
    const int tid = threadIdx.x;
    const int lane = tid & 63, wid = tid >> 6;
    const int wr = (wid >> 1) * 64, wc = (wid & 1) * 64;  // wave sub-tile origin
    const int g = lane >> 4, c = lane & 15;
    const int bm = blockIdx.y, bn = blockIdx.x;

    f32x4 acc[4][4] = {};

    for (int k0 = 0; k0 < 1024; k0 += 64) {
        __syncthreads();   // previous iter's fragment reads done before overwrite
        #pragma unroll
        for (int i = 0; i < 4; ++i) {
            int chunk = i * 256 + tid;            // 1024 chunks of 16B = 128x64 bf16
            int row = chunk >> 3, col = (chunk & 7) * 8;
            const u16* ga = A + (bm * 128 + row) * 1024 + k0 + col;
            const u16* gb = W + (bn * 128 + row) * 1024 + k0 + col;
            u16* la = As + (i * 256 + wid * 64) * 8;   // wave-uniform LDS base
            u16* lb = Bs + (i * 256 + wid * 64) * 8;
            __builtin_amdgcn_global_load_lds((const __attribute__((address_space(1))) u32*)ga,
                                             (__attribute__((address_space(3))) u32*)la, 16, 0, 0);
            __builtin_amdgcn_global_load_lds((const __attribute__((address_space(1))) u32*)gb,
                                             (__attribute__((address_space(3))) u32*)lb, 16, 0, 0);
        }
        __syncthreads();   // vmcnt(0) drain -> tile ready
        #pragma unroll
        for (int kk = 0; kk < 2; ++kk) {
            bf16x8 af[4], bf[4];
            #pragma unroll
            for (int i = 0; i < 4; ++i)
                af[i] = *(const bf16x8*)(As + (wr + i * 16 + c) * 64 + kk * 32 + g * 8);
            #pragma unroll
            for (int j = 0; j < 4; ++j)
                bf[j] = *(const bf16x8*)(Bs + (wc + j * 16 + c) * 64 + kk * 32 + g * 8);
            #pragma unroll
            for (int i = 0; i < 4; ++i)
                #pragma unroll
                for (int j = 0; j < 4; ++j)
                    acc[i][j] = __builtin_amdgcn_mfma_f32_16x16x32_bf16(af[i], bf[j], acc[i][j], 0, 0, 0);
        }
    }

    const int region = bn >> 3;                      // 0=Q 1=K 2=V
    const float* bias = region == 0 ? bq : (region == 1 ? bk : bv);
    #pragma unroll
    for (int i = 0; i < 4; ++i) {
        int m0 = bm * 128 + wr + i * 16 + g * 4;     // output row base (4 rows)
        int b = m0 >> 10, s0 = m0 & 1023;
        #pragma unroll
        for (int j = 0; j < 4; ++j) {
            int n = (bn & 7) * 128 + wc + j * 16 + c;  // col within region [0,1024)
            float bb = bias[n];
            int h = n >> 6, d = n & 63;
            int bh = b * 16 + h;
            if (region == 2) {
                U16x4 pk;
                pk.x = f2b(acc[i][j][0] + bb);
                pk.y = f2b(acc[i][j][1] + bb);
                pk.z = f2b(acc[i][j][2] + bb);
                pk.w = f2b(acc[i][j][3] + bb);
                *(U16x4*)(Vt + (bh * 64 + d) * 1024 + s0) = pk;   // s0 % 4 == 0
            } else if (region == 1) {
                #pragma unroll
                for (int r = 0; r < 4; ++r)
                    Ko[(bh * 1024 + s0 + r) * 64 + d] = f2b(acc[i][j][r] + bb);
            } else {
                #pragma unroll
                for (int r = 0; r < 4; ++r)           // fold 1/sqrt(D)=0.125 into Q (exact pow2)
                    Qo[(bh * 1024 + s0 + r) * 64 + d] = f2b((acc[i][j][r] + bb) * 0.125f);
            }
        }
    }
}

// ---------------- kernel 3: fused attention, post-softmax multiplicative link mask
// No online max (scores are O(10), exp() safe in f32); denominator accumulated
// per-lane, reduced once at the end. Swapped QK^T: sc=mfma(K,Q) -> D[key,q], so
// each lane owns q=lane&15 with 4 consecutive keys per reg: float4 link loads,
// packed u32 P writes, one ds_read_b128 for the PV A-fragment. Per-wave LDS,
// no barriers in the loop. 1024 blocks x 4 waves, 16 q-rows/wave.
__global__ __launch_bounds__(256) void attn_kernel(
    const u16* __restrict__ Q, const u16* __restrict__ K, const u16* __restrict__ Vt,
    const float* __restrict__ amask, const float* __restrict__ link,
    float* __restrict__ out)
{
    __shared__ u16 P[4][16 * 40];      // per-wave [q=16][key=32] padded to 40
    const int tid = threadIdx.x;
    const int lane = tid & 63, wid = tid >> 6;
    const int g = lane >> 4, c = lane & 15;

    // XCD-aware swizzle: blocks of batch b land on XCDs {2b, 2b+1} so each b's
    // 4 MB link mask is L2-resident on 2 XCDs (assumes blockIdx%8 -> XCD).
    int lin = blockIdx.x;
    int xcd = lin & 7, pos = lin >> 3;               // pos in [0,128)
    int b = xcd >> 1;
    int h = pos >> 3;                                // [0,16)
    int qt = ((pos & 7) << 1) | (xcd & 1);           // [0,16)
    int bh = b * 16 + h;
    const int qbase = qt * 64 + wid * 16;

    const u16* Qh = Q + bh * 65536;
    const u16* Kh = K + bh * 65536;
    const u16* Vh = Vt + bh * 65536;
    const float* mk = amask + b * 1024;
    const float* lkrow = link + (size_t)b * 1048576 + (size_t)(qbase + c) * 1024;

    bf16x8 qf[2];
    #pragma unroll
    for (int x = 0; x < 2; ++x)
        qf[x] = *(const bf16x8*)(Qh + (qbase + c) * 64 + x * 32 + g * 8);

    float lsum = 0.f;
    f32x4 ctx[4] = {};
    u16* Pb = (u16*)P[wid];

    for (int kv = 0; kv < 1024; kv += 32) {
        // scores^T: D[key(16), q(16)] x2 key-tiles, contraction over d=64
        f32x4 sc[2] = {};
        #pragma unroll
        for (int t = 0; t < 2; ++t)
            #pragma unroll
            for (int x = 0; x < 2; ++x) {
                bf16x8 kf = *(const bf16x8*)(Kh + (kv + t * 16 + c) * 64 + x * 32 + g * 8);
                sc[t] = __builtin_amdgcn_mfma_f32_16x16x32_bf16(kf, qf[x], sc[t], 0, 0, 0);
            }
        // lane holds S[q=qbase+c, key=kv+16t+4g+r], r=0..3 consecutive keys
        #pragma unroll
        for (int t = 0; t < 2; ++t) {
            float4 m4  = *(const float4*)(mk + kv + t * 16 + g * 4);
            float4 lk4 = *(const float4*)(lkrow + kv + t * 16 + g * 4);
            float e0 = __expf(sc[t][0] + m4.x);
            float e1 = __expf(sc[t][1] + m4.y);
            float e2 = __expf(sc[t][2] + m4.z);
            float e3 = __expf(sc[t][3] + m4.w);
            lsum += (e0 + e1) + (e2 + e3);           // denom WITHOUT link mask
            u32* pw = (u32*)(Pb + c * 40 + t * 16 + g * 4);
            pw[0] = pack2(e0 * lk4.x, e1 * lk4.y);
            pw[1] = pack2(e2 * lk4.z, e3 * lk4.w);
        }
        // PV: A-frag = P[q=c][key=g*8..g*8+7]  (in-order DS pipe, same wave -> no barrier)
        bf16x8 pf = *(const bf16x8*)(Pb + c * 40 + g * 8);
        #pragma unroll
        for (int n = 0; n < 4; ++n) {
            bf16x8 vf = *(const bf16x8*)(Vh + (n * 16 + c) * 1024 + kv + g * 8);
            ctx[n] = __builtin_amdgcn_mfma_f32_16x16x32_bf16(pf, vf, ctx[n], 0, 0, 0);
        }
    }

    // full row-sums: reduce the 4 key-groups (lanes c, 16+c, 32+c, 48+c)
    lsum += __shfl_xor(lsum, 16, 64);
    lsum += __shfl_xor(lsum, 32, 64);

    #pragma unroll
    for (int r = 0; r < 4; ++r) {
        float inv = 1.0f / __shfl(lsum, g * 4 + r, 16);  // sum for q=qbase+g*4+r
        int q = qbase + g * 4 + r;
        #pragma unroll
        for (int n = 0; n < 4; ++n)
            out[(size_t)b * 1048576 + (size_t)q * 1024 + h * 64 + n * 16 + c] = ctx[n][r] * inv;
    }
}

extern "C" void kernel_launch(void* const* d_in, const int* in_sizes, int n_in,
                              void* d_out, int out_size, void* d_ws, size_t ws_size,
                              hipStream_t stream)
{
    (void)in_sizes; (void)n_in; (void)out_size; (void)ws_size;
    const float* hs    = (const float*)d_in[0];
    const float* amask = (const float*)d_in[1];
    const float* link  = (const float*)d_in[2];
    const float* Wq    = (const float*)d_in[3];
    const float* bq    = (const float*)d_in[4];
    const float* Wk    = (const float*)d_in[5];
    const float* bk    = (const float*)d_in[6];
    const float* Wv    = (const float*)d_in[7];
    const float* bv    = (const float*)d_in[8];
    float* out = (float*)d_out;

    char* ws = (char*)d_ws;
    u16* hsb = (u16*)ws;                   // 8 MiB  [4096][1024] bf16
    u16* wb  = (u16*)(ws + (8u  << 20));   // 6 MiB  [3072][1024] bf16 (Wq|Wk|Wv)
    u16* Qb  = (u16*)(ws + (14u << 20));   // 8 MiB  [B,H,S,64]  (pre-scaled by 0.125)
    u16* Kb  = (u16*)(ws + (22u << 20));   // 8 MiB  [B,H,S,64]
    u16* Vtb = (u16*)(ws + (30u << 20));   // 8 MiB  [B,H,64,S]

    cvt_kernel<<<7168, 256, 0, stream>>>(hs, Wq, Wk, Wv, hsb, wb);
    qkv_gemm<<<dim3(24, 32), 256, 0, stream>>>(hsb, wb, bq, bk, bv, Qb, Kb, Vtb);
    attn_kernel<<<1024, 256, 0, stream>>>(Qb, Kb, Vtb, amask, link, out);
}

// Round 3
// 193.346 us; speedup vs baseline: 1.3299x; 1.1165x over previous
//
#include <hip/hip_runtime.h>
#include <hip/hip_bf16.h>
#include <cstdint>

typedef __attribute__((ext_vector_type(8))) __bf16 bf16x8;
typedef __attribute__((ext_vector_type(4))) float f32x4;
typedef unsigned short u16;
typedef unsigned int u32;

struct alignas(8) U16x4 { u16 x, y, z, w; };
struct alignas(8) U32x2 { u32 x, y; };

__device__ __forceinline__ u16 f2b(float x) {
    u32 u = __builtin_bit_cast(u32, x);
    u += 0x7fffu + ((u >> 16) & 1u);   // round-to-nearest-even
    return (u16)(u >> 16);
}
__device__ __forceinline__ u32 cvtpk(float lo, float hi) {
    u32 r;
    asm("v_cvt_pk_bf16_f32 %0, %1, %2" : "=v"(r) : "v"(lo), "v"(hi));
    return r;
}

// ---------------- kernel 1: f32 -> bf16 convert (hidden + concat weights) ----
__global__ __launch_bounds__(256) void cvt_kernel(
    const float* __restrict__ hs,
    const float* __restrict__ wq, const float* __restrict__ wk, const float* __restrict__ wv,
    u16* __restrict__ hsb, u16* __restrict__ wb)
{
    int i = blockIdx.x * 256 + threadIdx.x;       // float4 chunk index, exact grid
    const float4* src; u16* dst; int off;
    if (i < 1048576) { src = (const float4*)hs; dst = hsb; off = i; }
    else {
        int j = i - 1048576;                      // 3 * 262144 chunks
        int w = j >> 18;
        int o = j & 262143;
        src = (const float4*)(w == 0 ? wq : (w == 1 ? wk : wv));
        dst = wb + w * 1048576;
        off = o;
    }
    float4 v = src[off];
    U16x4 r; r.x = f2b(v.x); r.y = f2b(v.y); r.z = f2b(v.z); r.w = f2b(v.w);
    *(U16x4*)(dst + off * 4) = r;
}

// ---------------- kernel 2: QKV GEMM  C[4096,3072] = A[4096,1024] * W[3072,1024]^T
// m97 structure + bijective XCD swizzle. Q pre-scaled by 0.125; V written transposed.
__global__ __launch_bounds__(256) void qkv_gemm(
    const u16* __restrict__ A, const u16* __restrict__ W,
    const float* __restrict__ bq, const float* __restrict__ bk, const float* __restrict__ bv,
    u16* __restrict__ Qo, u16* __restrict__ Ko, u16* __restrict__ Vt)
{
    __shared__ u16 As[128 * 64];
    __shared__ u16 Bs[128 * 64];
    const int tid = threadIdx.x;
    const int lane = tid & 63, wid = tid >> 6;
    const int wr = (wid >> 1) * 64, wc = (wid & 1) * 64;  // wave sub-tile origin
    const int g = lane >> 4, c = lane & 15;

    // 768 blocks: XCD-bijective remap; within an XCD bn varies slowly -> 3 W-panels
    // (768 KB) L2-resident per XCD.
    int lin = blockIdx.y * 24 + blockIdx.x;
    int wg = (lin & 7) * 96 + (lin >> 3);
    const int bn = wg >> 5;      // 0..23
    const int bm = wg & 31;      // 0..31

    f32x4 acc[4][4] = {};

    for (int k0 = 0; k0 < 1024; k0 += 64) {
        __syncthreads();   // previous iter's fragment reads done before overwrite
        #pragma unroll
        for (int i = 0; i < 4; ++i) {
            int chunk = i * 256 + tid;            // 1024 chunks of 16B = 128x64 bf16
            int row = chunk >> 3, col = (chunk & 7) * 8;
            const u16* ga = A + (bm * 128 + row) * 1024 + k0 + col;
            const u16* gb = W + (bn * 128 + row) * 1024 + k0 + col;
            u16* la = As + (i * 256 + wid * 64) * 8;   // wave-uniform LDS base
            u16* lb = Bs + (i * 256 + wid * 64) * 8;
            __builtin_amdgcn_global_load_lds((const __attribute__((address_space(1))) u32*)ga,
                                             (__attribute__((address_space(3))) u32*)la, 16, 0, 0);
            __builtin_amdgcn_global_load_lds((const __attribute__((address_space(1))) u32*)gb,
                                             (__attribute__((address_space(3))) u32*)lb, 16, 0, 0);
        }
        __syncthreads();   // vmcnt(0) drain -> tile ready
        #pragma unroll
        for (int kk = 0; kk < 2; ++kk) {
            bf16x8 af[4], bf[4];
            #pragma unroll
            for (int i = 0; i < 4; ++i)
                af[i] = *(const bf16x8*)(As + (wr + i * 16 + c) * 64 + kk * 32 + g * 8);
            #pragma unroll
            for (int j = 0; j < 4; ++j)
                bf[j] = *(const bf16x8*)(Bs + (wc + j * 16 + c) * 64 + kk * 32 + g * 8);
            #pragma unroll
            for (int i = 0; i < 4; ++i)
                #pragma unroll
                for (int j = 0; j < 4; ++j)
                    acc[i][j] = __builtin_amdgcn_mfma_f32_16x16x32_bf16(af[i], bf[j], acc[i][j], 0, 0, 0);
        }
    }

    const int region = bn >> 3;                      // 0=Q 1=K 2=V
    const float* bias = region == 0 ? bq : (region == 1 ? bk : bv);
    #pragma unroll
    for (int i = 0; i < 4; ++i) {
        int m0 = bm * 128 + wr + i * 16 + g * 4;     // output row base (4 rows)
        int b = m0 >> 10, s0 = m0 & 1023;
        #pragma unroll
        for (int j = 0; j < 4; ++j) {
            int n = (bn & 7) * 128 + wc + j * 16 + c;  // col within region [0,1024)
            float bb = bias[n];
            int h = n >> 6, d = n & 63;
            int bh = b * 16 + h;
            if (region == 2) {
                U16x4 pk;
                pk.x = f2b(acc[i][j][0] + bb);
                pk.y = f2b(acc[i][j][1] + bb);
                pk.z = f2b(acc[i][j][2] + bb);
                pk.w = f2b(acc[i][j][3] + bb);
                *(U16x4*)(Vt + (bh * 64 + d) * 1024 + s0) = pk;   // s0 % 4 == 0
            } else if (region == 1) {
                #pragma unroll
                for (int r = 0; r < 4; ++r)
                    Ko[(bh * 1024 + s0 + r) * 64 + d] = f2b(acc[i][j][r] + bb);
            } else {
                #pragma unroll
                for (int r = 0; r < 4; ++r)           // fold 1/sqrt(D)=0.125 into Q (exact pow2)
                    Qo[(bh * 1024 + s0 + r) * 64 + d] = f2b((acc[i][j][r] + bb) * 0.125f);
            }
        }
    }
}

// ---------------- kernel 3: fused attention, post-softmax multiplicative link mask
// 512 blocks = (b, qtile of 128) x h; 4 waves x 32 q-rows. KVBLK=64.
// K register-double-buffered (prefetch next tile); V loaded per-tile after QK issue
// (latency hidden under exp/link phase); no K/V LDS staging (L2-resident).
// P per-wave in LDS, rows padded to 72 u16 (144 B) -> ~2-way banks on b128 reads.
#define ATTN_TILE(Kc, Kn, KV)                                                        \
  {                                                                                  \
    const int kv = (KV);                                                             \
    const int kvn = (kv + 64) & 1023;                                                \
    f32x4 lnk[2][4], m4[4];                                                          \
    _Pragma("unroll") for (int kt = 0; kt < 4; ++kt)                                 \
        m4[kt] = *(const f32x4*)(mk + kv + kt * 16 + g * 4);                         \
    _Pragma("unroll") for (int q2 = 0; q2 < 2; ++q2)                                 \
        _Pragma("unroll") for (int kt = 0; kt < 4; ++kt)                             \
            lnk[q2][kt] = *(const f32x4*)(lkq + (q2 * 16 + c) * 1024 + kv + kt * 16 + g * 4); \
    _Pragma("unroll") for (int kt = 0; kt < 4; ++kt)                                 \
        _Pragma("unroll") for (int x = 0; x < 2; ++x)                                \
            Kn[kt * 2 + x] = *(const bf16x8*)(Kh + (kvn + kt * 16 + c) * 64 + x * 32 + g * 8); \
    f32x4 sc[4][2] = {};                                                             \
    _Pragma("unroll") for (int kt = 0; kt < 4; ++kt)                                 \
        _Pragma("unroll") for (int q2 = 0; q2 < 2; ++q2)                             \
            _Pragma("unroll") for (int x = 0; x < 2; ++x)                            \
                sc[kt][q2] = __builtin_amdgcn_mfma_f32_16x16x32_bf16(Kc[kt * 2 + x], qf[q2][x], sc[kt][q2], 0, 0, 0); \
    bf16x8 vv[8];                                                                    \
    _Pragma("unroll") for (int dt = 0; dt < 4; ++dt)                                 \
        _Pragma("unroll") for (int kk = 0; kk < 2; ++kk)                             \
            vv[dt * 2 + kk] = *(const bf16x8*)(Vh + (dt * 16 + c) * 1024 + kv + kk * 32 + g * 8); \
    _Pragma("unroll") for (int q2 = 0; q2 < 2; ++q2)                                 \
        _Pragma("unroll") for (int kt = 0; kt < 4; ++kt) {                           \
            f32x4 s = sc[kt][q2];                                                    \
            float e0 = __expf(s[0] + m4[kt][0]);                                     \
            float e1 = __expf(s[1] + m4[kt][1]);                                     \
            float e2 = __expf(s[2] + m4[kt][2]);                                     \
            float e3 = __expf(s[3] + m4[kt][3]);                                     \
            lsum[q2] += (e0 + e1) + (e2 + e3);                                       \
            U32x2 pw;                                                                \
            pw.x = cvtpk(e0 * lnk[q2][kt][0], e1 * lnk[q2][kt][1]);                  \
            pw.y = cvtpk(e2 * lnk[q2][kt][2], e3 * lnk[q2][kt][3]);                  \
            *(U32x2*)(Pb + (q2 * 16 + c) * 72 + kt * 16 + g * 4) = pw;               \
        }                                                                            \
    _Pragma("unroll") for (int q2 = 0; q2 < 2; ++q2)                                 \
        _Pragma("unroll") for (int kk = 0; kk < 2; ++kk) {                           \
            bf16x8 pf = *(const bf16x8*)(Pb + (q2 * 16 + c) * 72 + kk * 32 + g * 8); \
            _Pragma("unroll") for (int dt = 0; dt < 4; ++dt)                         \
                ctx[q2][dt] = __builtin_amdgcn_mfma_f32_16x16x32_bf16(pf, vv[dt * 2 + kk], ctx[q2][dt], 0, 0, 0); \
        }                                                                            \
  }

__global__ __launch_bounds__(256, 2) void attn_kernel(
    const u16* __restrict__ Q, const u16* __restrict__ K, const u16* __restrict__ Vt,
    const float* __restrict__ amask, const float* __restrict__ link,
    float* __restrict__ out)
{
    __shared__ u16 P[4][32 * 72];      // per-wave [q=32][k=64] padded rows (144 B)
    const int tid = threadIdx.x;
    const int lane = tid & 63, wid = tid >> 6;
    const int g = lane >> 4, c = lane & 15;

    // XCD-bijective: logical (b, qt, h) lexicographic; each XCD owns one b and
    // 4 consecutive q-tiles (link slice 2 MB, L2-resident, shared by 16 heads).
    int hw = blockIdx.x;
    int logical = (hw & 7) * 64 + (hw >> 3);
    int b = logical >> 7;
    int qt = (logical >> 4) & 7;
    int h = logical & 15;
    int bh = b * 16 + h;
    const int qbase = qt * 128 + wid * 32;

    const u16* Qh = Q + bh * 65536;
    const u16* Kh = K + bh * 65536;
    const u16* Vh = Vt + bh * 65536;
    const float* mk = amask + b * 1024;
    const float* lkq = link + (size_t)b * 1048576 + (size_t)qbase * 1024;

    bf16x8 qf[2][2];
    #pragma unroll
    for (int q2 = 0; q2 < 2; ++q2)
        #pragma unroll
        for (int x = 0; x < 2; ++x)
            qf[q2][x] = *(const bf16x8*)(Qh + (qbase + q2 * 16 + c) * 64 + x * 32 + g * 8);

    float lsum[2] = {0.f, 0.f};
    f32x4 ctx[2][4] = {};
    u16* const Pb = &P[wid][0];

    bf16x8 K0[8], K1[8];
    #pragma unroll
    for (int kt = 0; kt < 4; ++kt)
        #pragma unroll
        for (int x = 0; x < 2; ++x)
            K0[kt * 2 + x] = *(const bf16x8*)(Kh + (kt * 16 + c) * 64 + x * 32 + g * 8);

    for (int it = 0; it < 8; ++it) {
        ATTN_TILE(K0, K1, it * 128);
        ATTN_TILE(K1, K0, it * 128 + 64);
    }

    #pragma unroll
    for (int q2 = 0; q2 < 2; ++q2) {
        lsum[q2] += __shfl_xor(lsum[q2], 16, 64);
        lsum[q2] += __shfl_xor(lsum[q2], 32, 64);
    }
    #pragma unroll
    for (int q2 = 0; q2 < 2; ++q2)
        #pragma unroll
        for (int r = 0; r < 4; ++r) {
            float inv = 1.0f / __shfl(lsum[q2], g * 4 + r, 16);
            int q = qbase + q2 * 16 + g * 4 + r;
            float* orow = out + (size_t)b * 1048576 + (size_t)q * 1024 + h * 64;
            #pragma unroll
            for (int dt = 0; dt < 4; ++dt)
                orow[dt * 16 + c] = ctx[q2][dt][r] * inv;
        }
}

extern "C" void kernel_launch(void* const* d_in, const int* in_sizes, int n_in,
                              void* d_out, int out_size, void* d_ws, size_t ws_size,
                              hipStream_t stream)
{
    (void)in_sizes; (void)n_in; (void)out_size; (void)ws_size;
    const float* hs    = (const float*)d_in[0];
    const float* amask = (const float*)d_in[1];
    const float* link  = (const float*)d_in[2];
    const float* Wq    = (const float*)d_in[3];
    const float* bq    = (const float*)d_in[4];
    const float* Wk    = (const float*)d_in[5];
    const float* bk    = (const float*)d_in[6];
    const float* Wv    = (const float*)d_in[7];
    const float* bv    = (const float*)d_in[8];
    float* out = (float*)d_out;

    char* ws = (char*)d_ws;
    u16* hsb = (u16*)ws;                   // 8 MiB  [4096][1024] bf16
    u16* wb  = (u16*)(ws + (8u  << 20));   // 6 MiB  [3072][1024] bf16 (Wq|Wk|Wv)
    u16* Qb  = (u16*)(ws + (14u << 20));   // 8 MiB  [B,H,S,64]  (pre-scaled by 0.125)
    u16* Kb  = (u16*)(ws + (22u << 20));   // 8 MiB  [B,H,S,64]
    u16* Vtb = (u16*)(ws + (30u << 20));   // 8 MiB  [B,H,64,S]

    cvt_kernel<<<7168, 256, 0, stream>>>(hs, Wq, Wk, Wv, hsb, wb);
    qkv_gemm<<<dim3(24, 32), 256, 0, stream>>>(hsb, wb, bq, bk, bv, Qb, Kb, Vtb);
    attn_kernel<<<512, 256, 0, stream>>>(Qb, Kb, Vtb, amask, link, out);
}

// Round 4
// 172.899 us; speedup vs baseline: 1.4871x; 1.1183x over previous
//
#include <hip/hip_runtime.h>
#include <hip/hip_bf16.h>
#include <cstdint>

typedef __attribute__((ext_vector_type(8))) __bf16 bf16x8;
typedef __attribute__((ext_vector_type(4))) float f32x4;
typedef unsigned short u16;
typedef unsigned int u32;

struct alignas(8) U16x4 { u16 x, y, z, w; };
struct alignas(8) U32x2 { u32 x, y; };

__device__ __forceinline__ u16 f2b(float x) {
    u32 u = __builtin_bit_cast(u32, x);
    u += 0x7fffu + ((u >> 16) & 1u);   // round-to-nearest-even
    return (u16)(u >> 16);
}
__device__ __forceinline__ u32 cvtpk(float lo, float hi) {
    u32 r;
    asm("v_cvt_pk_bf16_f32 %0, %1, %2" : "=v"(r) : "v"(lo), "v"(hi));
    return r;
}

// ---------------- kernel 1: f32 -> bf16 convert (hidden + concat weights) ----
__global__ __launch_bounds__(256) void cvt_kernel(
    const float* __restrict__ hs,
    const float* __restrict__ wq, const float* __restrict__ wk, const float* __restrict__ wv,
    u16* __restrict__ hsb, u16* __restrict__ wb)
{
    int i = blockIdx.x * 256 + threadIdx.x;       // float4 chunk index, exact grid
    const float4* src; u16* dst; int off;
    if (i < 1048576) { src = (const float4*)hs; dst = hsb; off = i; }
    else {
        int j = i - 1048576;                      // 3 * 262144 chunks
        int w = j >> 18;
        int o = j & 262143;
        src = (const float4*)(w == 0 ? wq : (w == 1 ? wk : wv));
        dst = wb + w * 1048576;
        off = o;
    }
    float4 v = src[off];
    U16x4 r; r.x = f2b(v.x); r.y = f2b(v.y); r.z = f2b(v.z); r.w = f2b(v.w);
    *(U16x4*)(dst + off * 4) = r;
}

// ---------------- kernel 2: QKV GEMM  C[4096,3072] = A[4096,1024] * W[3072,1024]^T
// m97 structure + bijective XCD swizzle. Q pre-scaled by 0.125; V written transposed.
__global__ __launch_bounds__(256) void qkv_gemm(
    const u16* __restrict__ A, const u16* __restrict__ W,
    const float* __restrict__ bq, const float* __restrict__ bk, const float* __restrict__ bv,
    u16* __restrict__ Qo, u16* __restrict__ Ko, u16* __restrict__ Vt)
{
    __shared__ u16 As[128 * 64];
    __shared__ u16 Bs[128 * 64];
    const int tid = threadIdx.x;
    const int lane = tid & 63, wid = tid >> 6;
    const int wr = (wid >> 1) * 64, wc = (wid & 1) * 64;  // wave sub-tile origin
    const int g = lane >> 4, c = lane & 15;

    // 768 blocks: XCD-bijective remap; within an XCD bn varies slowly -> 3 W-panels
    // (768 KB) L2-resident per XCD.
    int lin = blockIdx.y * 24 + blockIdx.x;
    int wg = (lin & 7) * 96 + (lin >> 3);
    const int bn = wg >> 5;      // 0..23
    const int bm = wg & 31;      // 0..31

    f32x4 acc[4][4] = {};

    for (int k0 = 0; k0 < 1024; k0 += 64) {
        __syncthreads();   // previous iter's fragment reads done before overwrite
        #pragma unroll
        for (int i = 0; i < 4; ++i) {
            int chunk = i * 256 + tid;            // 1024 chunks of 16B = 128x64 bf16
            int row = chunk >> 3, col = (chunk & 7) * 8;
            const u16* ga = A + (bm * 128 + row) * 1024 + k0 + col;
            const u16* gb = W + (bn * 128 + row) * 1024 + k0 + col;
            u16* la = As + (i * 256 + wid * 64) * 8;   // wave-uniform LDS base
            u16* lb = Bs + (i * 256 + wid * 64) * 8;
            __builtin_amdgcn_global_load_lds((const __attribute__((address_space(1))) u32*)ga,
                                             (__attribute__((address_space(3))) u32*)la, 16, 0, 0);
            __builtin_amdgcn_global_load_lds((const __attribute__((address_space(1))) u32*)gb,
                                             (__attribute__((address_space(3))) u32*)lb, 16, 0, 0);
        }
        __syncthreads();   // vmcnt(0) drain -> tile ready
        #pragma unroll
        for (int kk = 0; kk < 2; ++kk) {
            bf16x8 af[4], bf[4];
            #pragma unroll
            for (int i = 0; i < 4; ++i)
                af[i] = *(const bf16x8*)(As + (wr + i * 16 + c) * 64 + kk * 32 + g * 8);
            #pragma unroll
            for (int j = 0; j < 4; ++j)
                bf[j] = *(const bf16x8*)(Bs + (wc + j * 16 + c) * 64 + kk * 32 + g * 8);
            #pragma unroll
            for (int i = 0; i < 4; ++i)
                #pragma unroll
                for (int j = 0; j < 4; ++j)
                    acc[i][j] = __builtin_amdgcn_mfma_f32_16x16x32_bf16(af[i], bf[j], acc[i][j], 0, 0, 0);
        }
    }

    const int region = bn >> 3;                      // 0=Q 1=K 2=V
    const float* bias = region == 0 ? bq : (region == 1 ? bk : bv);
    #pragma unroll
    for (int i = 0; i < 4; ++i) {
        int m0 = bm * 128 + wr + i * 16 + g * 4;     // output row base (4 rows)
        int b = m0 >> 10, s0 = m0 & 1023;
        #pragma unroll
        for (int j = 0; j < 4; ++j) {
            int n = (bn & 7) * 128 + wc + j * 16 + c;  // col within region [0,1024)
            float bb = bias[n];
            int h = n >> 6, d = n & 63;
            int bh = b * 16 + h;
            if (region == 2) {
                U16x4 pk;
                pk.x = f2b(acc[i][j][0] + bb);
                pk.y = f2b(acc[i][j][1] + bb);
                pk.z = f2b(acc[i][j][2] + bb);
                pk.w = f2b(acc[i][j][3] + bb);
                *(U16x4*)(Vt + (bh * 64 + d) * 1024 + s0) = pk;   // s0 % 4 == 0
            } else if (region == 1) {
                #pragma unroll
                for (int r = 0; r < 4; ++r)
                    Ko[(bh * 1024 + s0 + r) * 64 + d] = f2b(acc[i][j][r] + bb);
            } else {
                #pragma unroll
                for (int r = 0; r < 4; ++r)           // fold 1/sqrt(D)=0.125 into Q (exact pow2)
                    Qo[(bh * 1024 + s0 + r) * 64 + d] = f2b((acc[i][j][r] + bb) * 0.125f);
            }
        }
    }
}

// ---------------- kernel 3: fused attention, post-softmax multiplicative link mask
// 512 blocks = (b, qtile of 128, h); 4 waves x 32 q-rows. KVBLK=64.
// LOW REGISTER PRESSURE structure (round-3 spilled ~150 MB scratch): per 16-key
// group, K frags are loaded, consumed by 4 MFMAs, exp/link applied and written
// to per-wave LDS immediately; PV streams V frags one at a time. Peak live
// ~100 VGPR -> no scratch. Latency hidden by 8 waves/CU TLP, not reg pipelining.
// No online max: scores are O(10), exp() safe in f32; denom reduced at the end.
__global__ __launch_bounds__(256) void attn_kernel(
    const u16* __restrict__ Q, const u16* __restrict__ K, const u16* __restrict__ Vt,
    const float* __restrict__ amask, const float* __restrict__ link,
    float* __restrict__ out)
{
    __shared__ u16 P[4][32 * 72];      // per-wave [q=32][k=64] rows padded to 72 u16
    const int tid = threadIdx.x;
    const int lane = tid & 63, wid = tid >> 6;
    const int g = lane >> 4, c = lane & 15;

    // XCD-bijective: each XCD owns one b and 4 consecutive q-tiles; link slice
    // (2 MB) L2-resident, shared by the 16 heads on that XCD.
    int hw = blockIdx.x;
    int logical = (hw & 7) * 64 + (hw >> 3);
    int b = logical >> 7;
    int qt = (logical >> 4) & 7;
    int h = logical & 15;
    int bh = b * 16 + h;
    const int qbase = qt * 128 + wid * 32;

    const u16* Qh = Q + bh * 65536;
    const u16* Kh = K + bh * 65536;
    const u16* Vh = Vt + bh * 65536;
    const float* mk = amask + b * 1024;
    const float* lkq = link + (size_t)b * 1048576 + (size_t)qbase * 1024;

    bf16x8 qf0x0 = *(const bf16x8*)(Qh + (qbase + c) * 64 + g * 8);
    bf16x8 qf0x1 = *(const bf16x8*)(Qh + (qbase + c) * 64 + 32 + g * 8);
    bf16x8 qf1x0 = *(const bf16x8*)(Qh + (qbase + 16 + c) * 64 + g * 8);
    bf16x8 qf1x1 = *(const bf16x8*)(Qh + (qbase + 16 + c) * 64 + 32 + g * 8);

    float lsum0 = 0.f, lsum1 = 0.f;
    f32x4 ctx[2][4] = {};
    u16* const Pb = &P[wid][0];

    for (int kv = 0; kv < 1024; kv += 64) {
        // ---- QK^T + softmax-numerator + link, one 16-key group at a time ----
        #pragma unroll
        for (int kt = 0; kt < 4; ++kt) {
            const u16* kp = Kh + (kv + kt * 16 + c) * 64 + g * 8;
            bf16x8 kf0 = *(const bf16x8*)(kp);
            bf16x8 kf1 = *(const bf16x8*)(kp + 32);
            f32x4 sc0 = {}, sc1 = {};
            sc0 = __builtin_amdgcn_mfma_f32_16x16x32_bf16(kf0, qf0x0, sc0, 0, 0, 0);
            sc0 = __builtin_amdgcn_mfma_f32_16x16x32_bf16(kf1, qf0x1, sc0, 0, 0, 0);
            sc1 = __builtin_amdgcn_mfma_f32_16x16x32_bf16(kf0, qf1x0, sc1, 0, 0, 0);
            sc1 = __builtin_amdgcn_mfma_f32_16x16x32_bf16(kf1, qf1x1, sc1, 0, 0, 0);
            f32x4 m4 = *(const f32x4*)(mk + kv + kt * 16 + g * 4);
            {   // q2 = 0
                f32x4 lk4 = *(const f32x4*)(lkq + c * 1024 + kv + kt * 16 + g * 4);
                float e0 = __expf(sc0[0] + m4[0]);
                float e1 = __expf(sc0[1] + m4[1]);
                float e2 = __expf(sc0[2] + m4[2]);
                float e3 = __expf(sc0[3] + m4[3]);
                lsum0 += (e0 + e1) + (e2 + e3);
                U32x2 pw;
                pw.x = cvtpk(e0 * lk4[0], e1 * lk4[1]);
                pw.y = cvtpk(e2 * lk4[2], e3 * lk4[3]);
                *(U32x2*)(Pb + c * 72 + kt * 16 + g * 4) = pw;
            }
            {   // q2 = 1
                f32x4 lk4 = *(const f32x4*)(lkq + (16 + c) * 1024 + kv + kt * 16 + g * 4);
                float e0 = __expf(sc1[0] + m4[0]);
                float e1 = __expf(sc1[1] + m4[1]);
                float e2 = __expf(sc1[2] + m4[2]);
                float e3 = __expf(sc1[3] + m4[3]);
                lsum1 += (e0 + e1) + (e2 + e3);
                U32x2 pw;
                pw.x = cvtpk(e0 * lk4[0], e1 * lk4[1]);
                pw.y = cvtpk(e2 * lk4[2], e3 * lk4[3]);
                *(U32x2*)(Pb + (16 + c) * 72 + kt * 16 + g * 4) = pw;
            }
        }
        // ---- PV: P back from LDS (in-order DS pipe, same wave -> no barrier) ----
        #pragma unroll
        for (int kk = 0; kk < 2; ++kk) {
            bf16x8 pf0 = *(const bf16x8*)(Pb + c * 72 + kk * 32 + g * 8);
            bf16x8 pf1 = *(const bf16x8*)(Pb + (16 + c) * 72 + kk * 32 + g * 8);
            #pragma unroll
            for (int dt = 0; dt < 4; ++dt) {
                bf16x8 vf = *(const bf16x8*)(Vh + (dt * 16 + c) * 1024 + kv + kk * 32 + g * 8);
                ctx[0][dt] = __builtin_amdgcn_mfma_f32_16x16x32_bf16(pf0, vf, ctx[0][dt], 0, 0, 0);
                ctx[1][dt] = __builtin_amdgcn_mfma_f32_16x16x32_bf16(pf1, vf, ctx[1][dt], 0, 0, 0);
            }
        }
    }

    lsum0 += __shfl_xor(lsum0, 16, 64);
    lsum0 += __shfl_xor(lsum0, 32, 64);
    lsum1 += __shfl_xor(lsum1, 16, 64);
    lsum1 += __shfl_xor(lsum1, 32, 64);

    #pragma unroll
    for (int r = 0; r < 4; ++r) {
        float inv0 = 1.0f / __shfl(lsum0, g * 4 + r, 16);
        float inv1 = 1.0f / __shfl(lsum1, g * 4 + r, 16);
        int q0 = qbase + g * 4 + r;
        float* orow0 = out + (size_t)b * 1048576 + (size_t)q0 * 1024 + h * 64;
        float* orow1 = orow0 + 16 * 1024;
        #pragma unroll
        for (int dt = 0; dt < 4; ++dt) {
            orow0[dt * 16 + c] = ctx[0][dt][r] * inv0;
            orow1[dt * 16 + c] = ctx[1][dt][r] * inv1;
        }
    }
}

extern "C" void kernel_launch(void* const* d_in, const int* in_sizes, int n_in,
                              void* d_out, int out_size, void* d_ws, size_t ws_size,
                              hipStream_t stream)
{
    (void)in_sizes; (void)n_in; (void)out_size; (void)ws_size;
    const float* hs    = (const float*)d_in[0];
    const float* amask = (const float*)d_in[1];
    const float* link  = (const float*)d_in[2];
    const float* Wq    = (const float*)d_in[3];
    const float* bq    = (const float*)d_in[4];
    const float* Wk    = (const float*)d_in[5];
    const float* bk    = (const float*)d_in[6];
    const float* Wv    = (const float*)d_in[7];
    const float* bv    = (const float*)d_in[8];
    float* out = (float*)d_out;

    char* ws = (char*)d_ws;
    u16* hsb = (u16*)ws;                   // 8 MiB  [4096][1024] bf16
    u16* wb  = (u16*)(ws + (8u  << 20));   // 6 MiB  [3072][1024] bf16 (Wq|Wk|Wv)
    u16* Qb  = (u16*)(ws + (14u << 20));   // 8 MiB  [B,H,S,64]  (pre-scaled by 0.125)
    u16* Kb  = (u16*)(ws + (22u << 20));   // 8 MiB  [B,H,S,64]
    u16* Vtb = (u16*)(ws + (30u << 20));   // 8 MiB  [B,H,64,S]

    cvt_kernel<<<7168, 256, 0, stream>>>(hs, Wq, Wk, Wv, hsb, wb);
    qkv_gemm<<<dim3(24, 32), 256, 0, stream>>>(hsb, wb, bq, bk, bv, Qb, Kb, Vtb);
    attn_kernel<<<512, 256, 0, stream>>>(Qb, Kb, Vtb, amask, link, out);
}